// Round 3
// baseline (95.682 us; speedup 1.0000x reference)
//
#include <hip/hip_runtime.h>
#include <math.h>

// Hungarian matcher cost matrix:
//   C[n,t] = 5*L1(xyxy) + 2*(focal@label[t]) - 2*GIoU + 9999*inner
// N = 14400, T = 1024, C = 91. Output [N,T] f32 (59 MB).
//
// R11: discriminating round. The rocprof top-5 shows only 256MiB harness
// poison fills (44-46us each); the matcher dispatch is provably <44us and
// by VALU arithmetic likely ~8-15us. R9/R10's __launch_bounds__(256,4)
// VGPR cap (128) may have caused spills (phase 2 wants ~140). This round:
//  - REVERT to uncapped launch_bounds(256) + R8's register row-constants
//    (known-good layout, ~140 VGPR -> 3 waves/SIMD, zero scratch).
//  - REVERT giou/Cv op association to R8's exact forms (isolate the
//    absmax 0.0625 -> 64 jump to the L1 identity alone).
//  - KEEP: single barrier (table phase computes sigmoid(obj) inline),
//    hoisted target-constant loads (overlap L2 latency with exp/log),
//    L1 via enclosure identity ((cw-iw)+(ch-ih)), TSTRIDE=12 gather
//    stride, nontemporal dwordx4 output stores.
// If dur_us stays ~95-97, the matcher is at its output-write floor and
// the bench is harness-fill-bound -> roofline.

#define BN 8
#define BT 256
#define VT 4
#define TSTRIDE 12   // floats per class row in s_tab (48 B)

typedef float f32x4 __attribute__((ext_vector_type(4)));

__global__ __launch_bounds__(BT) void matcher_kernel(
    const float* __restrict__ logits,   // [N, C]
    const float* __restrict__ boxes,    // [N, 4] cxcywh
    const float* __restrict__ points,   // [N, 2]
    const float* __restrict__ objs,     // [N, 1]
    const int*   __restrict__ labels,   // [T]
    const float* __restrict__ tboxes,   // [T, 4] cxcywh
    float* __restrict__ out,            // [N, T]
    int N, int C, int T)
{
    __shared__ __align__(16) float s_tab[96 * TSTRIDE];  // [class][row(+pad)]
    __shared__ __align__(16) float s_row[BN][8];  // x0,y0,x1,y1 | px,py,area1,-

    const int tid = threadIdx.x;
    const int rowBase = blockIdx.y * BN;
    const int t0 = tid * VT;

    // ---- target constants: issue global loads first so their L2 latency
    // overlaps the focal-table transcendentals ----
    int4 lv = *(const int4*)(labels + t0);
    float4 tbs[VT];
    tbs[0] = *(const float4*)(tboxes + 4 * (t0 + 0));
    tbs[1] = *(const float4*)(tboxes + 4 * (t0 + 1));
    tbs[2] = *(const float4*)(tboxes + 4 * (t0 + 2));
    tbs[3] = *(const float4*)(tboxes + 4 * (t0 + 3));
    int lab[VT] = {lv.x, lv.y, lv.z, lv.w};

    // ---- per-row constants (8 lanes) ----
    if (tid < BN) {
        int n = rowBase + tid;
        float4 b = *(const float4*)(boxes + 4 * n);
        float x0 = b.x - 0.5f * b.z;
        float y0 = b.y - 0.5f * b.w;
        float x1 = b.x + 0.5f * b.z;
        float y1 = b.y + 0.5f * b.w;
        s_row[tid][0] = x0;
        s_row[tid][1] = y0;
        s_row[tid][2] = x1;
        s_row[tid][3] = y1;
        float2 p = *(const float2*)(points + 2 * n);
        s_row[tid][4] = p.x;
        s_row[tid][5] = p.y;
        s_row[tid][6] = (x1 - x0) * (y1 - y0);
        s_row[tid][7] = 0.0f;   // unused
    }

    // ---- focal table, transposed write s_tab[c*TSTRIDE + r] ----
    // No dependence on s_row: sigmoid(obj) recomputed inline (L1-hit load).
    for (int idx = tid; idx < BN * C; idx += BT) {
        int r = idx / C;
        int c = idx - r * C;
        float lg = logits[(size_t)rowBase * C + idx];
        float po = __builtin_amdgcn_rcpf(1.0f + __expf(-objs[rowBase + r]));
        float ps = __builtin_amdgcn_rcpf(1.0f + __expf(-lg));
        float p = ps * po;
        float omp = 1.0f - p;
        float pos = 0.25f * (omp * omp) * (-__logf(p + 1e-8f));
        float neg = 0.75f * (p * p) * (-__logf(omp + 1e-8f));
        s_tab[c * TSTRIDE + r] = pos - neg;
    }
    __syncthreads();

    // ---- Phase 2: 4 target columns x 8 rows per thread ----
    float tx0[VT], ty0[VT], tx1[VT], ty1[VT], tarea[VT];
    #pragma unroll
    for (int j = 0; j < VT; ++j) {
        float4 tb = tbs[j];
        tx0[j] = tb.x - 0.5f * tb.z;
        ty0[j] = tb.y - 0.5f * tb.w;
        tx1[j] = tb.x + 0.5f * tb.z;
        ty1[j] = tb.y + 0.5f * tb.w;
        tarea[j] = (tx1[j] - tx0[j]) * (ty1[j] - ty0[j]);
    }

    // class costs: per j, all 8 rows in 2 ds_read_b128 (16B-aligned, 48B stride)
    float cc[VT][BN];
    #pragma unroll
    for (int j = 0; j < VT; ++j) {
        const float* tp = s_tab + lab[j] * TSTRIDE;
        float4 lo = *(const float4*)(tp);
        float4 hi = *(const float4*)(tp + 4);
        cc[j][0] = lo.x; cc[j][1] = lo.y; cc[j][2] = lo.z; cc[j][3] = lo.w;
        cc[j][4] = hi.x; cc[j][5] = hi.y; cc[j][6] = hi.z; cc[j][7] = hi.w;
    }

    // row constants -> registers (R8 layout: broadcast b128 reads, once)
    float rx0[BN], ry0[BN], rx1[BN], ry1[BN], rpx[BN], rpy[BN], ra1[BN];
    #pragma unroll
    for (int r = 0; r < BN; ++r) {
        float4 ra = *(const float4*)&s_row[r][0];
        float4 rb = *(const float4*)&s_row[r][4];
        rx0[r] = ra.x; ry0[r] = ra.y; rx1[r] = ra.z; ry1[r] = ra.w;
        rpx[r] = rb.x; rpy[r] = rb.y; ra1[r] = rb.z;
    }

    float* obase = out + (size_t)rowBase * T + t0;
    #pragma unroll
    for (int r = 0; r < BN; ++r) {
        float x0 = rx0[r], y0 = ry0[r], x1 = rx1[r], y1 = ry1[r];
        float px = rpx[r], py = rpy[r], a1 = ra1[r];

        f32x4 res;
        #pragma unroll
        for (int j = 0; j < VT; ++j) {
            // per-axis extents (shared by L1 / IoU / enclosure)
            float mnx0 = fminf(x0, tx0[j]), mxx0 = fmaxf(x0, tx0[j]);
            float mny0 = fminf(y0, ty0[j]), mxy0 = fmaxf(y0, ty0[j]);
            float mnx1 = fminf(x1, tx1[j]), mxx1 = fmaxf(x1, tx1[j]);
            float mny1 = fminf(y1, ty1[j]), mxy1 = fmaxf(y1, ty1[j]);

            float iw = mnx1 - mxx0;        // unclamped intersection extents
            float ih = mny1 - mxy0;
            float cw = mxx1 - mnx0;        // enclosure extents (>= 0)
            float ch = mxy1 - mny0;

            // L1(xyxy) == (cw - iw) + (ch - ih)  (max-min telescoping)
            float l1 = (cw - iw) + (ch - ih);

            float inter = fmaxf(iw, 0.0f) * fmaxf(ih, 0.0f);
            float uni = (a1 + tarea[j]) - inter;
            float carea = cw * ch;

            // giou with a single rcp (R8 association)
            float R = __builtin_amdgcn_rcpf(uni * carea);
            float giou = (inter * carea - uni * (carea - uni)) * R;

            // inner-point: exact reference op sequence (sign-exact)
            float left = px - tx0[j];
            float top = py - ty0[j];
            float right = tx1[j] - px;
            float bottom = ty1[j] - py;
            float mind = fminf(fminf(left, top), fminf(right, bottom));

            float Cv = fmaf(5.0f, l1, fmaf(2.0f, cc[j][r], -2.0f * giou));
            Cv += (mind >= 0.0f) ? 0.0f : 9999.0f;
            res[j] = Cv;
        }
        // 59 MB streaming output, zero reuse: bypass L2 retention
        __builtin_nontemporal_store(res, (f32x4*)(obase + (size_t)r * T));
    }
}

extern "C" void kernel_launch(void* const* d_in, const int* in_sizes, int n_in,
                              void* d_out, int out_size, void* d_ws, size_t ws_size,
                              hipStream_t stream) {
    const float* logits = (const float*)d_in[0];  // [bs,nq,nc]
    const float* boxes  = (const float*)d_in[1];  // [bs,nq,4]
    const float* points = (const float*)d_in[2];  // [bs,nq,2]
    const float* objs   = (const float*)d_in[3];  // [bs,nq,1]
    const int*   labels = (const int*)d_in[4];    // [T]
    const float* tboxes = (const float*)d_in[5];  // [T,4]
    float* out = (float*)d_out;

    int N = in_sizes[1] / 4;        // 14400
    int T = in_sizes[5] / 4;        // 1024
    int C = in_sizes[0] / N;        // 91

    dim3 grid(1, N / BN);           // 1800 blocks; each covers 8 rows x 1024 cols
    matcher_kernel<<<grid, BT, 0, stream>>>(logits, boxes, points, objs,
                                            labels, tboxes, out, N, C, T);
}